// Round 1
// baseline (6682.051 us; speedup 1.0000x reference)
//
#include <hip/hip_runtime.h>
#include <cstdint>
#include <cstddef>

#define B_  2
#define S_  2048
#define D_  1024
#define HH_ 4096
#define E_  8
#define RH_ 256

typedef float  f32x4 __attribute__((ext_vector_type(4)));
typedef float  f32x2 __attribute__((ext_vector_type(2)));
typedef __bf16 bf16x8 __attribute__((ext_vector_type(8)));
typedef __bf16 bf16x4 __attribute__((ext_vector_type(4)));

// ---------------------------------------------------------------- helpers
__device__ __forceinline__ void gload_lds16(const void* g, void* l) {
  __builtin_amdgcn_global_load_lds(
      (const __attribute__((address_space(1))) unsigned int*)g,
      (__attribute__((address_space(3))) unsigned int*)l, 16, 0, 0);
}

// stage a 128x64 bf16 tile (row-major, leading dim ldK elems) into LDS linearly
__device__ __forceinline__ void stage128x64(__bf16* s, const __bf16* g, int ldK, int t) {
  const int wv = t >> 6, l = t & 63;
#pragma unroll
  for (int p = 0; p < 4; ++p) {
    const int base = p * 256 + wv * 64;      // wave-uniform flat base
    const int flat = base + l;               // per-lane
    const int row = flat >> 3, c16 = flat & 7;
    gload_lds16(g + (size_t)row * ldK + c16 * 8, s + (size_t)base * 8);
  }
}

__device__ __forceinline__ void mfma_tile(const __bf16* sA, const __bf16* sB,
                                          f32x4 acc[4][4], int t) {
  const int w = t >> 6, l = t & 63;
  const int wr = w >> 1, wc = w & 1;
  const int fr = l & 15, fk = (l >> 4) * 8;
#pragma unroll
  for (int kk = 0; kk < 2; ++kk) {
    bf16x8 a[4], b[4];
#pragma unroll
    for (int m = 0; m < 4; ++m)
      a[m] = *(const bf16x8*)&sA[(64 * wr + 16 * m + fr) * 64 + kk * 32 + fk];
#pragma unroll
    for (int n = 0; n < 4; ++n)
      b[n] = *(const bf16x8*)&sB[(64 * wc + 16 * n + fr) * 64 + kk * 32 + fk];
#pragma unroll
    for (int m = 0; m < 4; ++m)
#pragma unroll
      for (int n = 0; n < 4; ++n)
        acc[m][n] = __builtin_amdgcn_mfma_f32_16x16x32_bf16(a[m], b[n], acc[m][n], 0, 0, 0);
  }
}

__device__ __forceinline__ void mfma_tile2(const __bf16* sA, const __bf16* sB,
                                           const __bf16* sC, f32x4 accg[4][4],
                                           f32x4 accu[4][4], int t) {
  const int w = t >> 6, l = t & 63;
  const int wr = w >> 1, wc = w & 1;
  const int fr = l & 15, fk = (l >> 4) * 8;
#pragma unroll
  for (int kk = 0; kk < 2; ++kk) {
    bf16x8 a[4], bg[4], bu[4];
#pragma unroll
    for (int m = 0; m < 4; ++m)
      a[m] = *(const bf16x8*)&sA[(64 * wr + 16 * m + fr) * 64 + kk * 32 + fk];
#pragma unroll
    for (int n = 0; n < 4; ++n) {
      bg[n] = *(const bf16x8*)&sB[(64 * wc + 16 * n + fr) * 64 + kk * 32 + fk];
      bu[n] = *(const bf16x8*)&sC[(64 * wc + 16 * n + fr) * 64 + kk * 32 + fk];
    }
#pragma unroll
    for (int m = 0; m < 4; ++m)
#pragma unroll
      for (int n = 0; n < 4; ++n) {
        accg[m][n] = __builtin_amdgcn_mfma_f32_16x16x32_bf16(a[m], bg[n], accg[m][n], 0, 0, 0);
        accu[m][n] = __builtin_amdgcn_mfma_f32_16x16x32_bf16(a[m], bu[n], accu[m][n], 0, 0, 0);
      }
  }
}

// ---------------------------------------------------------------- conversions
// 3-way split: src = hi + mid + lo to ~26 mantissa bits
__global__ void k_split3(const float* __restrict__ src, __bf16* __restrict__ hi,
                         __bf16* __restrict__ mid, __bf16* __restrict__ lo, int n4) {
  int i = blockIdx.x * 256 + threadIdx.x;
  if (i >= n4) return;
  f32x4 v = ((const f32x4*)src)[i];
  bf16x4 h, m, l;
#pragma unroll
  for (int j = 0; j < 4; ++j) {
    float x = v[j];
    __bf16 hb = (__bf16)x;
    float r1 = x - (float)hb;
    __bf16 mb = (__bf16)r1;
    float r2 = r1 - (float)mb;
    h[j] = hb; m[j] = mb; l[j] = (__bf16)r2;
  }
  ((bf16x4*)hi)[i] = h; ((bf16x4*)mid)[i] = m; ((bf16x4*)lo)[i] = l;
}

__global__ void k_tobf4(const float* __restrict__ src, __bf16* __restrict__ dst, int n4) {
  int i = blockIdx.x * 256 + threadIdx.x;
  if (i >= n4) return;
  f32x4 v = ((const f32x4*)src)[i];
  bf16x4 o;
#pragma unroll
  for (int j = 0; j < 4; ++j) o[j] = (__bf16)v[j];
  ((bf16x4*)dst)[i] = o;
}

// ---------------------------------------------------------------- gi GEMM
// gi = x @ W_ih^T + b_ih ; 6 split-pass pairs -> ~f32-exact. M=4096 N=768 K=1024
__global__ __launch_bounds__(256, 2)
void k_gemm_gi(const __bf16* __restrict__ xh, const __bf16* __restrict__ xm,
               const __bf16* __restrict__ xl, const __bf16* __restrict__ wh,
               const __bf16* __restrict__ wm, const __bf16* __restrict__ wl,
               const float* __restrict__ bih, float* __restrict__ gi) {
  __shared__ __bf16 sA[128 * 64], sB[128 * 64];
  const int t = threadIdx.x;
  const int m0 = blockIdx.x * 128, n0 = blockIdx.y * 128;
  f32x4 acc[4][4] = {};
  const __bf16* As[6] = {xh, xh, xm, xh, xm, xl};
  const __bf16* Bs[6] = {wh, wm, wh, wl, wm, wh};
  for (int p = 0; p < 6; ++p) {
    const __bf16* A = As[p];
    const __bf16* Bm = Bs[p];
    for (int kt = 0; kt < D_ / 64; ++kt) {
      __syncthreads();
      stage128x64(sA, A + (size_t)m0 * D_ + kt * 64, D_, t);
      stage128x64(sB, Bm + (size_t)n0 * D_ + kt * 64, D_, t);
      __syncthreads();
      mfma_tile(sA, sB, acc, t);
    }
  }
  const int w = t >> 6, l = t & 63, wr = w >> 1, wc = w & 1;
  const int col = l & 15, rb = (l >> 4) * 4;
#pragma unroll
  for (int m = 0; m < 4; ++m)
#pragma unroll
    for (int n = 0; n < 4; ++n)
#pragma unroll
      for (int i = 0; i < 4; ++i) {
        int gm = m0 + 64 * wr + 16 * m + rb + i;
        int gn = n0 + 64 * wc + 16 * n + col;
        gi[(size_t)gm * 768 + gn] = acc[m][n][i] + bih[gn];
      }
}

// ---------------------------------------------------------------- GRU scan
// 4 WGs: wg = b*2 + half. Each owns 128 units (384 W_hh rows) fully VGPR-resident.
// Cross-WG exchange of 128 h-values per step via agent-scope atomics + flag counters.
__global__ __launch_bounds__(512, 2)
void k_scan(const float* __restrict__ Whh, const float* __restrict__ gi,
            const float* __restrict__ bhh, float* __restrict__ hs,
            unsigned int* __restrict__ flags, float* __restrict__ newh) {
  const int wg = blockIdx.x;          // 0..3
  const int b = wg >> 1, half = wg & 1;
  const int partner = wg ^ 1;
  const int t = threadIdx.x;
  const int c = t & 3;                // col-slice: h[64c .. 64c+63]
  const int q = t >> 2;               // 0..127 local unit
  const int g = half * 128 + q;       // global unit 0..255

  __shared__ float hbuf[2][256];

  f32x2 w0[32], w1[32], w2[32];
  {
    const f32x4* p0 = (const f32x4*)(Whh + (size_t)(g) * 256 + 64 * c);
    const f32x4* p1 = (const f32x4*)(Whh + (size_t)(g + 256) * 256 + 64 * c);
    const f32x4* p2 = (const f32x4*)(Whh + (size_t)(g + 512) * 256 + 64 * c);
#pragma unroll
    for (int i = 0; i < 16; ++i) {
      f32x4 v0 = p0[i], v1 = p1[i], v2 = p2[i];
      w0[2 * i] = __builtin_shufflevector(v0, v0, 0, 1);
      w0[2 * i + 1] = __builtin_shufflevector(v0, v0, 2, 3);
      w1[2 * i] = __builtin_shufflevector(v1, v1, 0, 1);
      w1[2 * i + 1] = __builtin_shufflevector(v1, v1, 2, 3);
      w2[2 * i] = __builtin_shufflevector(v2, v2, 0, 1);
      w2[2 * i + 1] = __builtin_shufflevector(v2, v2, 2, 3);
    }
  }
  const float bh0 = bhh[g], bh1 = bhh[g + 256], bh2 = bhh[g + 512];
  if (t < 256) hbuf[0][t] = 0.f;
  float h_old = 0.f;  // identical across the 4 threads of a unit-quad
  const float* giB = gi + (size_t)(b * S_) * 768;
  __syncthreads();

  for (int s = 0; s < S_; ++s) {
    const int cur = s & 1, nxt = cur ^ 1;
    // input-side gates (redundant across quad; L1 broadcast)
    const float ir = giB[(size_t)s * 768 + g];
    const float iz = giB[(size_t)s * 768 + g + 256];
    const float in_ = giB[(size_t)s * 768 + g + 512];

    f32x2 a0 = {0.f, 0.f}, a1 = {0.f, 0.f}, a2 = {0.f, 0.f};
    const f32x4* hq = (const f32x4*)&hbuf[cur][64 * c];
#pragma unroll
    for (int i = 0; i < 16; ++i) {
      f32x4 hv = hq[i];
      f32x2 hA = __builtin_shufflevector(hv, hv, 0, 1);
      f32x2 hB = __builtin_shufflevector(hv, hv, 2, 3);
      a0 += w0[2 * i] * hA; a0 += w0[2 * i + 1] * hB;
      a1 += w1[2 * i] * hA; a1 += w1[2 * i + 1] * hB;
      a2 += w2[2 * i] * hA; a2 += w2[2 * i + 1] * hB;
    }
    float d0 = a0[0] + a0[1], d1 = a1[0] + a1[1], d2 = a2[0] + a2[1];
    d0 += __shfl_xor(d0, 1); d0 += __shfl_xor(d0, 2);
    d1 += __shfl_xor(d1, 1); d1 += __shfl_xor(d1, 2);
    d2 += __shfl_xor(d2, 1); d2 += __shfl_xor(d2, 2);

    const float r = 1.f / (1.f + expf(-(ir + d0 + bh0)));
    const float z = 1.f / (1.f + expf(-(iz + d1 + bh1)));
    const float n = tanhf(in_ + r * (d2 + bh2));
    const float hn = (1.f - z) * n + z * h_old;
    h_old = hn;

    if (c == 0) {
      hbuf[nxt][g] = hn;
      __hip_atomic_store(&hs[((size_t)s * 2 + b) * 256 + g], hn,
                         __ATOMIC_RELAXED, __HIP_MEMORY_SCOPE_AGENT);
      if (s == S_ - 1) newh[b * 256 + g] = hn;
    }
    __syncthreads();  // drains all waves' stores (vmcnt0 before barrier)
    if (t == 0) {
      __hip_atomic_store(&flags[wg], (unsigned)(s + 1),
                         __ATOMIC_RELEASE, __HIP_MEMORY_SCOPE_AGENT);
      while (__hip_atomic_load(&flags[partner], __ATOMIC_ACQUIRE,
                               __HIP_MEMORY_SCOPE_AGENT) < (unsigned)(s + 1)) {}
    }
    __syncthreads();
    if (t < 128) {
      const int pg = (half ^ 1) * 128 + t;
      hbuf[nxt][pg] = __hip_atomic_load(&hs[((size_t)s * 2 + b) * 256 + pg],
                                        __ATOMIC_RELAXED, __HIP_MEMORY_SCOPE_AGENT);
    }
    __syncthreads();
  }
}

// ---------------------------------------------------------------- logits
__global__ void k_logits(const float* __restrict__ hs, const float* __restrict__ Wr,
                         const float* __restrict__ br, float* __restrict__ logits) {
  const int idx = blockIdx.x * 256 + threadIdx.x;  // 32768
  const int tok = idx >> 3, e = idx & 7;
  const int s = tok & (S_ - 1), b = tok >> 11;
  const f32x4* h4 = (const f32x4*)&hs[((size_t)s * 2 + b) * 256];
  const f32x4* w4 = (const f32x4*)&Wr[e * 256];
  float acc = 0.f;
#pragma unroll 8
  for (int k = 0; k < 64; ++k) {
    f32x4 a = h4[k], w = w4[k];
    acc += a[0] * w[0] + a[1] * w[1] + a[2] * w[2] + a[3] * w[3];
  }
  logits[idx] = acc + br[e];
}

// ---------------------------------------------------------------- router finish
__global__ void k_finish(const float* __restrict__ logits, float* __restrict__ wdense,
                         float* __restrict__ partials) {
  const int tok = blockIdx.x * 256 + threadIdx.x;  // 4096
  float p[8];
  float mx = -1e30f;
#pragma unroll
  for (int e = 0; e < 8; ++e) { p[e] = logits[tok * 8 + e]; mx = fmaxf(mx, p[e]); }
  float sum = 0.f;
#pragma unroll
  for (int e = 0; e < 8; ++e) { p[e] = expf(p[e] - mx); sum += p[e]; }
  const float inv = 1.f / sum;
#pragma unroll
  for (int e = 0; e < 8; ++e) p[e] *= inv;
  int i1 = 0;
#pragma unroll
  for (int e = 1; e < 8; ++e) if (p[e] > p[i1]) i1 = e;   // ties -> lower index
  int i2 = -1; float p2 = -1.f;
#pragma unroll
  for (int e = 0; e < 8; ++e) if (e != i1 && p[e] > p2) { p2 = p[e]; i2 = e; }
  const float inv2 = 1.f / (p[i1] + p2);
#pragma unroll
  for (int e = 0; e < 8; ++e)
    wdense[tok * 8 + e] = (e == i1) ? p[i1] * inv2 : (e == i2 ? p2 * inv2 : 0.f);

  __shared__ float ps[256][8];
#pragma unroll
  for (int e = 0; e < 8; ++e) ps[threadIdx.x][e] = p[e];
  __syncthreads();
  for (int st = 128; st >= 1; st >>= 1) {
    if (threadIdx.x < st)
#pragma unroll
      for (int e = 0; e < 8; ++e) ps[threadIdx.x][e] += ps[threadIdx.x + st][e];
    __syncthreads();
  }
  if (threadIdx.x == 0)
#pragma unroll
    for (int e = 0; e < 8; ++e) partials[blockIdx.x * 8 + e] = ps[0][e];
}

__global__ void k_aux(const float* __restrict__ partials, float* __restrict__ aux) {
  __shared__ float m2[8];
  const int e = threadIdx.x;
  if (e < 8) {
    float s = 0.f;
    for (int bl = 0; bl < 16; ++bl) s += partials[bl * 8 + e];
    const float mean = s / 4096.f;
    m2[e] = mean * mean;
  }
  __syncthreads();
  if (threadIdx.x == 0) {
    float s = 0.f;
#pragma unroll
    for (int i = 0; i < 8; ++i) s += m2[i];
    aux[0] = 8.f * s;
  }
}

// ---------------------------------------------------------------- experts
__global__ __launch_bounds__(256, 2)
void k_gateup(const __bf16* __restrict__ xbf, const __bf16* __restrict__ Wgbf,
              const __bf16* __restrict__ Wubf, __bf16* __restrict__ Hbf) {
  __shared__ __bf16 sA[128 * 64], sB[128 * 64], sC[128 * 64];
  const int t = threadIdx.x;
  const int m0 = blockIdx.x * 128, n0 = blockIdx.y * 128;
  f32x4 ag[4][4] = {}, au[4][4] = {};
  for (int kt = 0; kt < D_ / 64; ++kt) {
    __syncthreads();
    stage128x64(sA, xbf + (size_t)m0 * D_ + kt * 64, D_, t);
    stage128x64(sB, Wgbf + (size_t)n0 * D_ + kt * 64, D_, t);
    stage128x64(sC, Wubf + (size_t)n0 * D_ + kt * 64, D_, t);
    __syncthreads();
    mfma_tile2(sA, sB, sC, ag, au, t);
  }
  const int w = t >> 6, l = t & 63, wr = w >> 1, wc = w & 1;
  const int col = l & 15, rb = (l >> 4) * 4;
#pragma unroll
  for (int m = 0; m < 4; ++m)
#pragma unroll
    for (int n = 0; n < 4; ++n)
#pragma unroll
      for (int i = 0; i < 4; ++i) {
        int gm = m0 + 64 * wr + 16 * m + rb + i;
        int gn = n0 + 64 * wc + 16 * n + col;
        float gv = ag[m][n][i], uv = au[m][n][i];
        float h = 0.5f * gv * (1.f + erff(gv * 0.70710678118654752440f)) * uv;
        Hbf[(size_t)gm * HH_ + gn] = (__bf16)h;
      }
}

__global__ __launch_bounds__(256, 2)
void k_down(const __bf16* __restrict__ Hbf, const __bf16* __restrict__ Wdbf,
            const float* __restrict__ wdense, float* __restrict__ out, int e) {
  __shared__ __bf16 sA[128 * 64], sB[128 * 64];
  const int t = threadIdx.x;
  const int m0 = blockIdx.x * 128, n0 = blockIdx.y * 128;
  f32x4 acc[4][4] = {};
  for (int kt = 0; kt < HH_ / 64; ++kt) {
    __syncthreads();
    stage128x64(sA, Hbf + (size_t)m0 * HH_ + kt * 64, HH_, t);
    stage128x64(sB, Wdbf + (size_t)n0 * HH_ + kt * 64, HH_, t);
    __syncthreads();
    mfma_tile(sA, sB, acc, t);
  }
  const int w = t >> 6, l = t & 63, wr = w >> 1, wc = w & 1;
  const int col = l & 15, rb = (l >> 4) * 4;
#pragma unroll
  for (int m = 0; m < 4; ++m)
#pragma unroll
    for (int i = 0; i < 4; ++i) {
      const int gm = m0 + 64 * wr + 16 * m + rb + i;
      const float wv = wdense[gm * 8 + e];
#pragma unroll
      for (int n = 0; n < 4; ++n) {
        const int gn = n0 + 64 * wc + 16 * n + col;
        out[(size_t)gm * 1024 + gn] += wv * acc[m][n][i];
      }
    }
}

// ---------------------------------------------------------------- launch
extern "C" void kernel_launch(void* const* d_in, const int* in_sizes, int n_in,
                              void* d_out, int out_size, void* d_ws, size_t ws_size,
                              hipStream_t stream) {
  (void)in_sizes; (void)n_in; (void)out_size; (void)ws_size;
  const float* x    = (const float*)d_in[0];
  const float* Wg   = (const float*)d_in[1];
  const float* Wu   = (const float*)d_in[2];
  const float* Wd   = (const float*)d_in[3];
  const float* Wih  = (const float*)d_in[4];
  const float* Whh  = (const float*)d_in[5];
  const float* bih  = (const float*)d_in[6];
  const float* bhh  = (const float*)d_in[7];
  const float* Wr   = (const float*)d_in[8];
  const float* br   = (const float*)d_in[9];

  float* out    = (float*)d_out;                       // (B,S,D)
  float* logits = out + (size_t)B_ * S_ * D_;          // (B,S,E)
  float* newh   = logits + (size_t)B_ * S_ * E_;       // (B,RH)
  float* aux    = newh + (size_t)B_ * RH_;             // scalar

  char* ws = (char*)d_ws;
  size_t off = 0;
  auto alloc = [&](size_t bytes) { size_t r = off; off += (bytes + 255) & ~(size_t)255; return r; };
  const size_t XN = (size_t)B_ * S_ * D_;              // 4,194,304
  const size_t WIN = (size_t)3 * RH_ * D_;             // 786,432

  __bf16* xh  = (__bf16*)(ws + alloc(XN * 2));
  __bf16* xm  = (__bf16*)(ws + alloc(XN * 2));
  __bf16* xl  = (__bf16*)(ws + alloc(XN * 2));
  __bf16* wih_h = (__bf16*)(ws + alloc(WIN * 2));
  __bf16* wih_m = (__bf16*)(ws + alloc(WIN * 2));
  __bf16* wih_l = (__bf16*)(ws + alloc(WIN * 2));
  float*  gi  = (float*)(ws + alloc((size_t)B_ * S_ * 768 * 4));
  float*  hs  = (float*)(ws + alloc((size_t)S_ * B_ * RH_ * 4));
  unsigned int* flags = (unsigned int*)(ws + alloc(256));
  float*  wdense = (float*)(ws + alloc((size_t)B_ * S_ * E_ * 4));
  float*  partials = (float*)(ws + alloc(16 * 8 * 4));
  __bf16* Wgbf = (__bf16*)(ws + alloc((size_t)HH_ * D_ * 2));
  __bf16* Wubf = (__bf16*)(ws + alloc((size_t)HH_ * D_ * 2));
  __bf16* Wdbf = (__bf16*)(ws + alloc((size_t)D_ * HH_ * 2));
  __bf16* Hbf  = (__bf16*)(ws + alloc((size_t)B_ * S_ * HH_ * 2));

  hipMemsetAsync(flags, 0, 256, stream);
  hipMemsetAsync(out, 0, XN * 4, stream);

  // splits
  k_split3<<<dim3((XN / 4 + 255) / 256), 256, 0, stream>>>(x, xh, xm, xl, (int)(XN / 4));
  k_split3<<<dim3((WIN / 4 + 255) / 256), 256, 0, stream>>>(Wih, wih_h, wih_m, wih_l, (int)(WIN / 4));

  // gi GEMM (f32-exact via 3-way split)
  k_gemm_gi<<<dim3(32, 6), 256, 0, stream>>>(xh, xm, xl, wih_h, wih_m, wih_l, bih, gi);

  // sequential GRU scan
  k_scan<<<dim3(4), 512, 0, stream>>>(Whh, gi, bhh, hs, flags, newh);

  // router outputs
  k_logits<<<dim3(128), 256, 0, stream>>>(hs, Wr, br, logits);
  k_finish<<<dim3(16), 256, 0, stream>>>(logits, wdense, partials);
  k_aux<<<dim3(1), 64, 0, stream>>>(partials, aux);

  // dense experts (bf16 MFMA), accumulate weighted into out
  const int n4w = (int)((size_t)HH_ * D_ / 4);
  for (int e = 0; e < E_; ++e) {
    k_tobf4<<<dim3((n4w + 255) / 256), 256, 0, stream>>>(Wg + (size_t)e * HH_ * D_, Wgbf, n4w);
    k_tobf4<<<dim3((n4w + 255) / 256), 256, 0, stream>>>(Wu + (size_t)e * HH_ * D_, Wubf, n4w);
    k_tobf4<<<dim3((n4w + 255) / 256), 256, 0, stream>>>(Wd + (size_t)e * D_ * HH_, Wdbf, n4w);
    k_gateup<<<dim3(32, 32), 256, 0, stream>>>(xh, Wgbf, Wubf, Hbf);
    k_down<<<dim3(32, 8), 256, 0, stream>>>(Hbf, Wdbf, wdense, out, e);
  }
}

// Round 2
// 4641.034 us; speedup vs baseline: 1.4398x; 1.4398x over previous
//
#include <hip/hip_runtime.h>
#include <cstdint>
#include <cstddef>

#define B_  2
#define S_  2048
#define D_  1024
#define HH_ 4096
#define E_  8
#define RH_ 256

typedef float  f32x4 __attribute__((ext_vector_type(4)));
typedef __bf16 bf16x8 __attribute__((ext_vector_type(8)));
typedef __bf16 bf16x4 __attribute__((ext_vector_type(4)));

// ---------------------------------------------------------------- helpers
__device__ __forceinline__ void gload_lds16(const void* g, void* l) {
  __builtin_amdgcn_global_load_lds(
      (const __attribute__((address_space(1))) unsigned int*)g,
      (__attribute__((address_space(3))) unsigned int*)l, 16, 0, 0);
}

// stage a 128x64 bf16 tile (row-major, leading dim ldK elems) into LDS linearly
__device__ __forceinline__ void stage128x64(__bf16* s, const __bf16* g, int ldK, int t) {
  const int wv = t >> 6, l = t & 63;
#pragma unroll
  for (int p = 0; p < 4; ++p) {
    const int base = p * 256 + wv * 64;      // wave-uniform flat base
    const int flat = base + l;               // per-lane
    const int row = flat >> 3, c16 = flat & 7;
    gload_lds16(g + (size_t)row * ldK + c16 * 8, s + (size_t)base * 8);
  }
}

__device__ __forceinline__ void mfma_tile(const __bf16* sA, const __bf16* sB,
                                          f32x4 acc[4][4], int t) {
  const int w = t >> 6, l = t & 63;
  const int wr = w >> 1, wc = w & 1;
  const int fr = l & 15, fk = (l >> 4) * 8;
#pragma unroll
  for (int kk = 0; kk < 2; ++kk) {
    bf16x8 a[4], b[4];
#pragma unroll
    for (int m = 0; m < 4; ++m)
      a[m] = *(const bf16x8*)&sA[(64 * wr + 16 * m + fr) * 64 + kk * 32 + fk];
#pragma unroll
    for (int n = 0; n < 4; ++n)
      b[n] = *(const bf16x8*)&sB[(64 * wc + 16 * n + fr) * 64 + kk * 32 + fk];
#pragma unroll
    for (int m = 0; m < 4; ++m)
#pragma unroll
      for (int n = 0; n < 4; ++n)
        acc[m][n] = __builtin_amdgcn_mfma_f32_16x16x32_bf16(a[m], b[n], acc[m][n], 0, 0, 0);
  }
}

__device__ __forceinline__ void mfma_tile2(const __bf16* sA, const __bf16* sB,
                                           const __bf16* sC, f32x4 accg[4][4],
                                           f32x4 accu[4][4], int t) {
  const int w = t >> 6, l = t & 63;
  const int wr = w >> 1, wc = w & 1;
  const int fr = l & 15, fk = (l >> 4) * 8;
#pragma unroll
  for (int kk = 0; kk < 2; ++kk) {
    bf16x8 a[4], bg[4], bu[4];
#pragma unroll
    for (int m = 0; m < 4; ++m)
      a[m] = *(const bf16x8*)&sA[(64 * wr + 16 * m + fr) * 64 + kk * 32 + fk];
#pragma unroll
    for (int n = 0; n < 4; ++n) {
      bg[n] = *(const bf16x8*)&sB[(64 * wc + 16 * n + fr) * 64 + kk * 32 + fk];
      bu[n] = *(const bf16x8*)&sC[(64 * wc + 16 * n + fr) * 64 + kk * 32 + fk];
    }
#pragma unroll
    for (int m = 0; m < 4; ++m)
#pragma unroll
      for (int n = 0; n < 4; ++n) {
        accg[m][n] = __builtin_amdgcn_mfma_f32_16x16x32_bf16(a[m], bg[n], accg[m][n], 0, 0, 0);
        accu[m][n] = __builtin_amdgcn_mfma_f32_16x16x32_bf16(a[m], bu[n], accu[m][n], 0, 0, 0);
      }
  }
}

// ---------------------------------------------------------------- conversions
// 3-way split: src = hi + mid + lo to ~26 mantissa bits
__global__ void k_split3(const float* __restrict__ src, __bf16* __restrict__ hi,
                         __bf16* __restrict__ mid, __bf16* __restrict__ lo, int n4) {
  int i = blockIdx.x * 256 + threadIdx.x;
  if (i >= n4) return;
  f32x4 v = ((const f32x4*)src)[i];
  bf16x4 h, m, l;
#pragma unroll
  for (int j = 0; j < 4; ++j) {
    float x = v[j];
    __bf16 hb = (__bf16)x;
    float r1 = x - (float)hb;
    __bf16 mb = (__bf16)r1;
    float r2 = r1 - (float)mb;
    h[j] = hb; m[j] = mb; l[j] = (__bf16)r2;
  }
  ((bf16x4*)hi)[i] = h; ((bf16x4*)mid)[i] = m; ((bf16x4*)lo)[i] = l;
}

__global__ void k_tobf4(const float* __restrict__ src, __bf16* __restrict__ dst, int n4) {
  int i = blockIdx.x * 256 + threadIdx.x;
  if (i >= n4) return;
  f32x4 v = ((const f32x4*)src)[i];
  bf16x4 o;
#pragma unroll
  for (int j = 0; j < 4; ++j) o[j] = (__bf16)v[j];
  ((bf16x4*)dst)[i] = o;
}

// ---------------------------------------------------------------- gi GEMM
// gi = x @ W_ih^T + b_ih ; 6 split-pass pairs -> ~f32-exact. M=4096 N=768 K=1024
__global__ __launch_bounds__(256, 2)
void k_gemm_gi(const __bf16* __restrict__ xh, const __bf16* __restrict__ xm,
               const __bf16* __restrict__ xl, const __bf16* __restrict__ wh,
               const __bf16* __restrict__ wm, const __bf16* __restrict__ wl,
               const float* __restrict__ bih, float* __restrict__ gi) {
  __shared__ __bf16 sA[128 * 64], sB[128 * 64];
  const int t = threadIdx.x;
  const int m0 = blockIdx.x * 128, n0 = blockIdx.y * 128;
  f32x4 acc[4][4] = {};
  const __bf16* As[6] = {xh, xh, xm, xh, xm, xl};
  const __bf16* Bs[6] = {wh, wm, wh, wl, wm, wh};
  for (int p = 0; p < 6; ++p) {
    const __bf16* A = As[p];
    const __bf16* Bm = Bs[p];
    for (int kt = 0; kt < D_ / 64; ++kt) {
      __syncthreads();
      stage128x64(sA, A + (size_t)m0 * D_ + kt * 64, D_, t);
      stage128x64(sB, Bm + (size_t)n0 * D_ + kt * 64, D_, t);
      __syncthreads();
      mfma_tile(sA, sB, acc, t);
    }
  }
  const int w = t >> 6, l = t & 63, wr = w >> 1, wc = w & 1;
  const int col = l & 15, rb = (l >> 4) * 4;
#pragma unroll
  for (int m = 0; m < 4; ++m)
#pragma unroll
    for (int n = 0; n < 4; ++n)
#pragma unroll
      for (int i = 0; i < 4; ++i) {
        int gm = m0 + 64 * wr + 16 * m + rb + i;
        int gn = n0 + 64 * wc + 16 * n + col;
        gi[(size_t)gm * 768 + gn] = acc[m][n][i] + bih[gn];
      }
}

// ---------------------------------------------------------------- GRU scan v2
// 2 WGs per batch, each owns 384 W_hh rows fully VGPR-resident (192 VGPRs via
// waves_per_eu(2,2) -> 256-reg budget). Cross-WG h exchange: data-as-flag
// (hs NaN-poisoned each launch; writer relaxed-agent store; reader polls until
// !isnan). Blocks {0,8},{1,9}: same XCD under round-robin blockIdx%8 mapping.
__global__ __attribute__((amdgpu_flat_work_group_size(512, 512)))
__attribute__((amdgpu_waves_per_eu(2, 2)))
void k_scan(const float* __restrict__ Whh, const float* __restrict__ gi,
            const float* __restrict__ bhh, float* __restrict__ hs,
            float* __restrict__ newh) {
  int role;
  switch (blockIdx.x) {
    case 0: role = 0; break;   // batch 0, half 0
    case 8: role = 1; break;   // batch 0, half 1
    case 1: role = 2; break;   // batch 1, half 0
    case 9: role = 3; break;   // batch 1, half 1
    default: return;
  }
  const int b = role >> 1, half = role & 1;
  const int t = threadIdx.x;
  const int c = t & 3;                 // col slice: h[64c..64c+63]
  const int q = t >> 2;                // local unit 0..127
  const int g = half * 128 + q;        // global unit 0..255

  __shared__ __align__(16) float hbuf[2][256];

  // weights: rotated chunk order (j+2c)&15 -> conflict-free LDS reads later
  f32x4 w0[16], w1[16], w2[16];
#pragma unroll
  for (int j = 0; j < 16; ++j) {
    const int jr = (j + 2 * c) & 15;
    const size_t colo = (size_t)(64 * c + 4 * jr);
    w0[j] = *(const f32x4*)(Whh + (size_t)g * 256 + colo);
    w1[j] = *(const f32x4*)(Whh + (size_t)(g + 256) * 256 + colo);
    w2[j] = *(const f32x4*)(Whh + (size_t)(g + 512) * 256 + colo);
  }
  const float bh0 = bhh[g], bh1 = bhh[g + 256], bh2 = bhh[g + 512];
  if (t < 256) hbuf[0][t] = 0.f;
  float h_old = 0.f;                   // replicated across the quad
  const float* giB = gi + (size_t)(b * S_) * 768;
  float* hsB = hs + (size_t)b * 256;   // row stride 512 floats
  // software-pipelined gi loads
  float ir = giB[g], iz = giB[g + 256], in_ = giB[g + 512];
  __syncthreads();

  for (int s = 0; s < S_; ++s) {
    const int cur = s & 1, nxt = cur ^ 1;
    const int sn = (s + 1 < S_) ? s + 1 : s;
    const float irn = giB[(size_t)sn * 768 + g];
    const float izn = giB[(size_t)sn * 768 + g + 256];
    const float inn = giB[(size_t)sn * 768 + g + 512];

    f32x4 a0 = {0.f, 0.f, 0.f, 0.f}, a1 = a0, a2 = a0;
#pragma unroll
    for (int j = 0; j < 16; ++j) {
      const int jr = (j + 2 * c) & 15;
      f32x4 hv = *(const f32x4*)&hbuf[cur][64 * c + 4 * jr];
      a0 += w0[j] * hv; a1 += w1[j] * hv; a2 += w2[j] * hv;
    }
    float d0 = (a0[0] + a0[1]) + (a0[2] + a0[3]);
    float d1 = (a1[0] + a1[1]) + (a1[2] + a1[3]);
    float d2 = (a2[0] + a2[1]) + (a2[2] + a2[3]);
    d0 += __shfl_xor(d0, 1); d0 += __shfl_xor(d0, 2);
    d1 += __shfl_xor(d1, 1); d1 += __shfl_xor(d1, 2);
    d2 += __shfl_xor(d2, 1); d2 += __shfl_xor(d2, 2);

    const float r = 1.f / (1.f + expf(-(ir + d0 + bh0)));
    const float z = 1.f / (1.f + expf(-(iz + d1 + bh1)));
    const float n = tanhf(in_ + r * (d2 + bh2));
    const float hn = (1.f - z) * n + z * h_old;
    h_old = hn;

    float* hsrow = hsB + (size_t)s * 512;
    if (c == 0) {
      hbuf[nxt][g] = hn;               // own half for next step (LDS)
      __hip_atomic_store(hsrow + g, hn, __ATOMIC_RELAXED, __HIP_MEMORY_SCOPE_AGENT);
    }
    if (t < 128) {                     // poll partner half: data IS the flag
      const int pg = (half ^ 1) * 128 + t;
      float v;
      do {
        v = __hip_atomic_load(hsrow + pg, __ATOMIC_RELAXED, __HIP_MEMORY_SCOPE_AGENT);
      } while (v != v);                // NaN-poisoned until written
      hbuf[nxt][pg] = v;
    }
    ir = irn; iz = izn; in_ = inn;
    __syncthreads();
  }
  if (c == 0) newh[b * 256 + g] = h_old;
}

// ---------------------------------------------------------------- logits
__global__ void k_logits(const float* __restrict__ hs, const float* __restrict__ Wr,
                         const float* __restrict__ br, float* __restrict__ logits) {
  const int idx = blockIdx.x * 256 + threadIdx.x;  // 32768
  const int tok = idx >> 3, e = idx & 7;
  const int s = tok & (S_ - 1), b = tok >> 11;
  const f32x4* h4 = (const f32x4*)&hs[((size_t)s * 2 + b) * 256];
  const f32x4* w4 = (const f32x4*)&Wr[e * 256];
  float acc = 0.f;
#pragma unroll 8
  for (int k = 0; k < 64; ++k) {
    f32x4 a = h4[k], w = w4[k];
    acc += a[0] * w[0] + a[1] * w[1] + a[2] * w[2] + a[3] * w[3];
  }
  logits[idx] = acc + br[e];
}

// ---------------------------------------------------------------- router finish
__global__ void k_finish(const float* __restrict__ logits, float* __restrict__ wdense,
                         float* __restrict__ partials) {
  const int tok = blockIdx.x * 256 + threadIdx.x;  // 4096
  float p[8];
  float mx = -1e30f;
#pragma unroll
  for (int e = 0; e < 8; ++e) { p[e] = logits[tok * 8 + e]; mx = fmaxf(mx, p[e]); }
  float sum = 0.f;
#pragma unroll
  for (int e = 0; e < 8; ++e) { p[e] = expf(p[e] - mx); sum += p[e]; }
  const float inv = 1.f / sum;
#pragma unroll
  for (int e = 0; e < 8; ++e) p[e] *= inv;
  int i1 = 0;
#pragma unroll
  for (int e = 1; e < 8; ++e) if (p[e] > p[i1]) i1 = e;   // ties -> lower index
  int i2 = -1; float p2 = -1.f;
#pragma unroll
  for (int e = 0; e < 8; ++e) if (e != i1 && p[e] > p2) { p2 = p[e]; i2 = e; }
  const float inv2 = 1.f / (p[i1] + p2);
#pragma unroll
  for (int e = 0; e < 8; ++e)
    wdense[tok * 8 + e] = (e == i1) ? p[i1] * inv2 : (e == i2 ? p2 * inv2 : 0.f);

  __shared__ float ps[256][8];
#pragma unroll
  for (int e = 0; e < 8; ++e) ps[threadIdx.x][e] = p[e];
  __syncthreads();
  for (int st = 128; st >= 1; st >>= 1) {
    if (threadIdx.x < st)
#pragma unroll
      for (int e = 0; e < 8; ++e) ps[threadIdx.x][e] += ps[threadIdx.x + st][e];
    __syncthreads();
  }
  if (threadIdx.x == 0)
#pragma unroll
    for (int e = 0; e < 8; ++e) partials[blockIdx.x * 8 + e] = ps[0][e];
}

__global__ void k_aux(const float* __restrict__ partials, float* __restrict__ aux) {
  __shared__ float m2[8];
  const int e = threadIdx.x;
  if (e < 8) {
    float s = 0.f;
    for (int bl = 0; bl < 16; ++bl) s += partials[bl * 8 + e];
    const float mean = s / 4096.f;
    m2[e] = mean * mean;
  }
  __syncthreads();
  if (threadIdx.x == 0) {
    float s = 0.f;
#pragma unroll
    for (int i = 0; i < 8; ++i) s += m2[i];
    aux[0] = 8.f * s;
  }
}

// ---------------------------------------------------------------- experts
__global__ __launch_bounds__(256, 2)
void k_gateup(const __bf16* __restrict__ xbf, const __bf16* __restrict__ Wgbf,
              const __bf16* __restrict__ Wubf, __bf16* __restrict__ Hbf) {
  __shared__ __bf16 sA[128 * 64], sB[128 * 64], sC[128 * 64];
  const int t = threadIdx.x;
  const int m0 = blockIdx.x * 128, n0 = blockIdx.y * 128;
  f32x4 ag[4][4] = {}, au[4][4] = {};
  for (int kt = 0; kt < D_ / 64; ++kt) {
    __syncthreads();
    stage128x64(sA, xbf + (size_t)m0 * D_ + kt * 64, D_, t);
    stage128x64(sB, Wgbf + (size_t)n0 * D_ + kt * 64, D_, t);
    stage128x64(sC, Wubf + (size_t)n0 * D_ + kt * 64, D_, t);
    __syncthreads();
    mfma_tile2(sA, sB, sC, ag, au, t);
  }
  const int w = t >> 6, l = t & 63, wr = w >> 1, wc = w & 1;
  const int col = l & 15, rb = (l >> 4) * 4;
#pragma unroll
  for (int m = 0; m < 4; ++m)
#pragma unroll
    for (int n = 0; n < 4; ++n)
#pragma unroll
      for (int i = 0; i < 4; ++i) {
        int gm = m0 + 64 * wr + 16 * m + rb + i;
        int gn = n0 + 64 * wc + 16 * n + col;
        float gv = ag[m][n][i], uv = au[m][n][i];
        float h = 0.5f * gv * (1.f + erff(gv * 0.70710678118654752440f)) * uv;
        Hbf[(size_t)gm * HH_ + gn] = (__bf16)h;
      }
}

__global__ __launch_bounds__(256, 2)
void k_down(const __bf16* __restrict__ Hbf, const __bf16* __restrict__ Wdbf,
            const float* __restrict__ wdense, float* __restrict__ out, int e) {
  __shared__ __bf16 sA[128 * 64], sB[128 * 64];
  const int t = threadIdx.x;
  const int m0 = blockIdx.x * 128, n0 = blockIdx.y * 128;
  f32x4 acc[4][4] = {};
  for (int kt = 0; kt < HH_ / 64; ++kt) {
    __syncthreads();
    stage128x64(sA, Hbf + (size_t)m0 * HH_ + kt * 64, HH_, t);
    stage128x64(sB, Wdbf + (size_t)n0 * HH_ + kt * 64, HH_, t);
    __syncthreads();
    mfma_tile(sA, sB, acc, t);
  }
  const int w = t >> 6, l = t & 63, wr = w >> 1, wc = w & 1;
  const int col = l & 15, rb = (l >> 4) * 4;
#pragma unroll
  for (int m = 0; m < 4; ++m)
#pragma unroll
    for (int i = 0; i < 4; ++i) {
      const int gm = m0 + 64 * wr + 16 * m + rb + i;
      const float wv = wdense[gm * 8 + e];
#pragma unroll
      for (int n = 0; n < 4; ++n) {
        const int gn = n0 + 64 * wc + 16 * n + col;
        out[(size_t)gm * 1024 + gn] += wv * acc[m][n][i];
      }
    }
}

// ---------------------------------------------------------------- launch
extern "C" void kernel_launch(void* const* d_in, const int* in_sizes, int n_in,
                              void* d_out, int out_size, void* d_ws, size_t ws_size,
                              hipStream_t stream) {
  (void)in_sizes; (void)n_in; (void)out_size; (void)ws_size;
  const float* x    = (const float*)d_in[0];
  const float* Wg   = (const float*)d_in[1];
  const float* Wu   = (const float*)d_in[2];
  const float* Wd   = (const float*)d_in[3];
  const float* Wih  = (const float*)d_in[4];
  const float* Whh  = (const float*)d_in[5];
  const float* bih  = (const float*)d_in[6];
  const float* bhh  = (const float*)d_in[7];
  const float* Wr   = (const float*)d_in[8];
  const float* br   = (const float*)d_in[9];

  float* out    = (float*)d_out;                       // (B,S,D)
  float* logits = out + (size_t)B_ * S_ * D_;          // (B,S,E)
  float* newh   = logits + (size_t)B_ * S_ * E_;       // (B,RH)
  float* aux    = newh + (size_t)B_ * RH_;             // scalar

  char* ws = (char*)d_ws;
  size_t off = 0;
  auto alloc = [&](size_t bytes) { size_t r = off; off += (bytes + 255) & ~(size_t)255; return r; };
  const size_t XN = (size_t)B_ * S_ * D_;              // 4,194,304
  const size_t WIN = (size_t)3 * RH_ * D_;             // 786,432

  __bf16* xh  = (__bf16*)(ws + alloc(XN * 2));
  __bf16* xm  = (__bf16*)(ws + alloc(XN * 2));
  __bf16* xl  = (__bf16*)(ws + alloc(XN * 2));
  __bf16* wih_h = (__bf16*)(ws + alloc(WIN * 2));
  __bf16* wih_m = (__bf16*)(ws + alloc(WIN * 2));
  __bf16* wih_l = (__bf16*)(ws + alloc(WIN * 2));
  float*  gi  = (float*)(ws + alloc((size_t)B_ * S_ * 768 * 4));
  float*  hs  = (float*)(ws + alloc((size_t)S_ * B_ * RH_ * 4));
  float*  wdense = (float*)(ws + alloc((size_t)B_ * S_ * E_ * 4));
  float*  partials = (float*)(ws + alloc(16 * 8 * 4));
  __bf16* Wgbf = (__bf16*)(ws + alloc((size_t)HH_ * D_ * 2));
  __bf16* Wubf = (__bf16*)(ws + alloc((size_t)HH_ * D_ * 2));
  __bf16* Wdbf = (__bf16*)(ws + alloc((size_t)D_ * HH_ * 2));
  __bf16* Hbf  = (__bf16*)(ws + alloc((size_t)B_ * S_ * HH_ * 2));

  hipMemsetAsync(out, 0, XN * 4, stream);
  // NaN-poison hs: the data-as-flag protocol's "not yet written" marker
  hipMemsetAsync(hs, 0xFF, (size_t)S_ * B_ * RH_ * 4, stream);

  // splits
  k_split3<<<dim3((XN / 4 + 255) / 256), 256, 0, stream>>>(x, xh, xm, xl, (int)(XN / 4));
  k_split3<<<dim3((WIN / 4 + 255) / 256), 256, 0, stream>>>(Wih, wih_h, wih_m, wih_l, (int)(WIN / 4));

  // gi GEMM (f32-exact via 3-way split)
  k_gemm_gi<<<dim3(32, 6), 256, 0, stream>>>(xh, xm, xl, wih_h, wih_m, wih_l, bih, gi);

  // sequential GRU scan (blocks 0,8 = batch0; 1,9 = batch1; rest exit)
  k_scan<<<dim3(16), 512, 0, stream>>>(Whh, gi, bhh, hs, newh);

  // router outputs
  k_logits<<<dim3(128), 256, 0, stream>>>(hs, Wr, br, logits);
  k_finish<<<dim3(16), 256, 0, stream>>>(logits, wdense, partials);
  k_aux<<<dim3(1), 64, 0, stream>>>(partials, aux);

  // dense experts (bf16 MFMA), accumulate weighted into out
  const int n4w = (int)((size_t)HH_ * D_ / 4);
  for (int e = 0; e < E_; ++e) {
    k_tobf4<<<dim3((n4w + 255) / 256), 256, 0, stream>>>(Wg + (size_t)e * HH_ * D_, Wgbf, n4w);
    k_tobf4<<<dim3((n4w + 255) / 256), 256, 0, stream>>>(Wu + (size_t)e * HH_ * D_, Wubf, n4w);
    k_tobf4<<<dim3((n4w + 255) / 256), 256, 0, stream>>>(Wd + (size_t)e * D_ * HH_, Wdbf, n4w);
    k_gateup<<<dim3(32, 32), 256, 0, stream>>>(xh, Wgbf, Wubf, Hbf);
    k_down<<<dim3(32, 8), 256, 0, stream>>>(Hbf, Wdbf, wdense, out, e);
  }
}